// Round 10
// baseline (3777.044 us; speedup 1.0000x reference)
//
#include <hip/hip_runtime.h>

// ---------------- constants ----------------
#define NN    100000      // nodes per batch
#define NE    400000      // edges per batch
#define NG    4096        // graphs
#define LL    5
#define MPAD  100096      // 782*128
#define NCHUNK 98         // ceil(NN/1024)

typedef unsigned short u16;
typedef __attribute__((ext_vector_type(8))) _Float16 half8;
typedef __attribute__((ext_vector_type(4))) _Float16 hv4;
typedef __attribute__((ext_vector_type(4))) float float4v;
typedef __attribute__((ext_vector_type(8))) short short8v;

// bf16 decode/encode (for dtype probe + bf16-output fallback)
__device__ __forceinline__ float b2f(u16 u){
  union { float f; unsigned u; } c; c.u = ((unsigned)u)<<16; return c.f;
}
__device__ __forceinline__ u16 f2b(float f){
  union { float f; unsigned u; } c; c.f = f;
  unsigned x = c.u;
  return (u16)((x + 0x7fffu + ((x>>16)&1u)) >> 16);
}
// fp16 decode/encode (pipeline precision)
__device__ __forceinline__ float h2f(u16 u){
  union { u16 s; _Float16 h; } c; c.s = u; return (float)c.h;
}
__device__ __forceinline__ u16 f2h(float f){
  union { u16 s; _Float16 h; } c; c.h = (_Float16)f; return c.s;
}
__device__ __forceinline__ void g2l16(const u16* g, u16* l){
  __builtin_amdgcn_global_load_lds((const __attribute__((address_space(1))) void*)g,
                                   (__attribute__((address_space(3))) void*)l, 16, 0, 0);
}

// ---------------- dtype detection / normalization ----------------
__global__ __launch_bounds__(256) void detect_dtype(const u16* __restrict__ p, int* __restrict__ flag){
  int i = blockIdx.x*256 + threadIdx.x;   // 16 blocks -> 4096 halves
  float v = b2f(p[i]);
  if (!(fabsf(v) <= 1e4f)) atomicOr(flag, 1);
}
__global__ __launch_bounds__(256) void cvt_param(const void* __restrict__ src, u16* __restrict__ dst,
                                                 int n, const int* __restrict__ flag){
  int i = blockIdx.x*256 + threadIdx.x;
  if (i >= n) return;
  float v = (*flag) ? ((const float*)src)[i] : b2f(((const u16*)src)[i]);
  dst[i] = f2h(v);
}

// ---------------- small utility kernels ----------------
__global__ __launch_bounds__(256) void zero32(unsigned* __restrict__ p, int n){
  int i = blockIdx.x*256 + threadIdx.x;
  if (i < n) p[i] = 0u;
}

// transpose+pad: dst[l][n][k] = src[l][k][n], zero outside (fp16 elements)
__global__ __launch_bounds__(256) void tpad(const u16* __restrict__ src, u16* __restrict__ dst,
                                            int L, int K, int N, int Kp, int Np){
  int idx = blockIdx.x*256 + threadIdx.x;
  if (idx >= L*Np*Kp) return;
  int l = idx/(Np*Kp); int r = idx - l*Np*Kp; int n = r/Kp; int k = r - n*Kp;
  dst[idx] = (n<N && k<K) ? src[(l*K + k)*N + n] : (u16)0;
}

// ecomb[l][c][0:320] = eemb1[l][c/3] + eemb2[l][c%3], cols>=300 zero. fp16.
__global__ __launch_bounds__(256) void ecomb_build(const u16* __restrict__ ee1, const u16* __restrict__ ee2,
                                                   u16* __restrict__ ec){
  int idx = blockIdx.x*256 + threadIdx.x;
  if (idx >= LL*18*160) return;
  int l = idx/(18*160); int r = idx - l*18*160; int c = r/160; int p = r - c*160;
  int a0 = c/3, a1 = c - a0*3;
  u16 o0=0,o1=0;
  if (p < 150){
    int d = 2*p;
    o0 = f2h(h2f(ee1[(l*6+a0)*300+d  ]) + h2f(ee2[(l*3+a1)*300+d  ]));
    o1 = f2h(h2f(ee1[(l*6+a0)*300+d+1]) + h2f(ee2[(l*3+a1)*300+d+1]));
  }
  ((ushort2*)ec)[idx] = make_ushort2(o0,o1);
}

// h[n][0:320] = atom_emb1[x[n,0]] + atom_emb2[x[n,1]]; pads zero (fp16)
__global__ __launch_bounds__(256) void node_init(const int* __restrict__ x, const u16* __restrict__ ae1,
                                                 const u16* __restrict__ ae2, u16* __restrict__ h){
  int idx = blockIdx.x*256 + threadIdx.x;
  if (idx >= MPAD*160) return;
  int n = idx/160, p = idx - n*160;
  u16 o0=0,o1=0;
  if (n < NN && p < 150){
    int a = x[2*n], ch = x[2*n+1];
    int d = 2*p;
    o0 = f2h(h2f(ae1[a*300+d  ]) + h2f(ae2[ch*300+d  ]));
    o1 = f2h(h2f(ae1[a*300+d+1]) + h2f(ae2[ch*300+d+1]));
  }
  ((ushort2*)h)[idx] = make_ushort2(o0,o1);
}

// ---------------- CSR build ----------------
__global__ __launch_bounds__(256) void hist(const int* __restrict__ ei, int* __restrict__ counts){
  int e = blockIdx.x*256 + threadIdx.x;
  if (e >= NE) return;
  atomicAdd(&counts[ei[NE + e]], 1);
}
__global__ __launch_bounds__(256) void scan_chunks(const int* __restrict__ counts, int* __restrict__ csums){
  __shared__ int sd[256];
  int base = blockIdx.x*1024;
  int s = 0;
  for (int i = threadIdx.x; i < 1024; i += 256){ int g = base+i; if (g < NN) s += counts[g]; }
  sd[threadIdx.x] = s; __syncthreads();
  for (int off=128; off>0; off>>=1){ if (threadIdx.x < off) sd[threadIdx.x] += sd[threadIdx.x+off]; __syncthreads(); }
  if (threadIdx.x == 0) csums[blockIdx.x] = sd[0];
}
__global__ __launch_bounds__(128) void scan_base(const int* __restrict__ csums, int* __restrict__ cbase,
                                                 int* __restrict__ offsets){
  __shared__ int sd[128];
  int tid = threadIdx.x;
  int v = (tid < NCHUNK) ? csums[tid] : 0;
  sd[tid] = v; __syncthreads();
  for (int off=1; off<128; off<<=1){
    int t = (tid >= off) ? sd[tid-off] : 0; __syncthreads();
    sd[tid] += t; __syncthreads();
  }
  if (tid < NCHUNK) cbase[tid] = sd[tid] - v;
  if (tid == 0) offsets[NN] = sd[NCHUNK-1];
}
__global__ __launch_bounds__(256) void scan_final(const int* __restrict__ counts, const int* __restrict__ cbase,
                                                  int* __restrict__ offsets){
  __shared__ int sd[256];
  int tid = threadIdx.x;
  int base = blockIdx.x*1024 + tid*4;
  int v0 = (base   < NN) ? counts[base  ] : 0;
  int v1 = (base+1 < NN) ? counts[base+1] : 0;
  int v2 = (base+2 < NN) ? counts[base+2] : 0;
  int v3 = (base+3 < NN) ? counts[base+3] : 0;
  int s = v0+v1+v2+v3;
  sd[tid] = s; __syncthreads();
  for (int off=1; off<256; off<<=1){
    int t = (tid >= off) ? sd[tid-off] : 0; __syncthreads();
    sd[tid] += t; __syncthreads();
  }
  int run = cbase[blockIdx.x] + sd[tid] - s;
  if (base   < NN){ offsets[base  ] = run; } run += v0;
  if (base+1 < NN){ offsets[base+1] = run; } run += v1;
  if (base+2 < NN){ offsets[base+2] = run; } run += v2;
  if (base+3 < NN){ offsets[base+3] = run; }
}
// pack src*32+combo so aggregate needs ONE load per edge
__global__ __launch_bounds__(256) void fill_perm(const int* __restrict__ ei, const int* __restrict__ ea,
                                                 const int* __restrict__ offsets,
                                                 int* __restrict__ cursor, int* __restrict__ pk){
  int e = blockIdx.x*256 + threadIdx.x;
  if (e >= NE) return;
  int d = ei[NE + e];
  int src = ei[e];
  int c = ea[2*e]*3 + ea[2*e+1];
  int pos = offsets[d] + atomicAdd(&cursor[d], 1);
  pk[pos] = src*32 + c;
}

// ---------------- aggregation + FUSED BN/ReLU of the source (r9-proven) ---------
__global__ __launch_bounds__(256) void aggregate(
    const u16* __restrict__ h, const u16* __restrict__ ecL,
    const int* __restrict__ offsets, const int* __restrict__ pk,
    u16* __restrict__ agg,
    const float* __restrict__ sc, const float* __restrict__ sh, int dobn)
{
  __shared__ u16 ecs[18*320];
  for (int i = threadIdx.x; i < 18*160; i += 256)
    ((ushort2*)ecs)[i] = ((const ushort2*)ecL)[i];
  __syncthreads();
  int node = blockIdx.x*4 + (threadIdx.x>>6);
  int lane = threadIdx.x & 63;
  bool tl = lane < 16;
  // per-lane BN constants (sc/sh zeroed by bn_finalize for d>=300 -> pads stay 0)
  hv4 s0 = (hv4)(_Float16)1, t0 = (hv4)(_Float16)0;
  hv4 s1 = (hv4)(_Float16)1, t1 = (hv4)(_Float16)0;
  if (dobn){
    #pragma unroll
    for (int j=0;j<4;++j){ s0[j] = (_Float16)sc[lane*4+j]; t0[j] = (_Float16)sh[lane*4+j]; }
    if (tl){
      #pragma unroll
      for (int j=0;j<4;++j){ s1[j] = (_Float16)sc[256+lane*4+j]; t1[j] = (_Float16)sh[256+lane*4+j]; }
    }
  }
  const hv4 hz = (hv4)(_Float16)0;
  auto bn0 = [&](hv4 v)->hv4 {
    if (!dobn) return v;
    return __builtin_elementwise_max(v*s0 + t0, hz);
  };
  auto bn1 = [&](hv4 v)->hv4 {
    if (!dobn) return v;
    return __builtin_elementwise_max(v*s1 + t1, hz);
  };
  const hv4* h4 = (const hv4*)h;
  const hv4* e4 = (const hv4*)ecs;
  long base = (long)node*80;
  hv4 acc0, acc1 = hz;
  // self: relu(BN(z_self)) + ec[12] (bond 4, dir 0)
  acc0 = bn0(h4[base + lane]) + e4[12*80 + lane];
  if (tl) acc1 = bn1(h4[base + 64 + lane]) + e4[12*80 + 64 + lane];
  if (node < NN){
    int s = offsets[node], en = offsets[node+1];
    int i = s;
    while (i + 3 < en){
      int p0 = pk[i], p1 = pk[i+1], p2 = pk[i+2], p3 = pk[i+3]; i += 4;
      long b0 = (long)(p0>>5)*80, b1 = (long)(p1>>5)*80;
      long b2 = (long)(p2>>5)*80, b3 = (long)(p3>>5)*80;
      int c0 = (p0&31)*80, c1 = (p1&31)*80, c2 = (p2&31)*80, c3 = (p3&31)*80;
      hv4 a0 = bn0(h4[b0+lane]), a1 = bn0(h4[b1+lane]);
      hv4 a2 = bn0(h4[b2+lane]), a3 = bn0(h4[b3+lane]);
      hv4 e0 = e4[c0+lane], e1 = e4[c1+lane], e2 = e4[c2+lane], e3 = e4[c3+lane];
      acc0 += (a0+e0); acc0 += (a1+e1); acc0 += (a2+e2); acc0 += (a3+e3);
      if (tl){
        hv4 x0 = bn1(h4[b0+64+lane]), x1 = bn1(h4[b1+64+lane]);
        hv4 x2 = bn1(h4[b2+64+lane]), x3 = bn1(h4[b3+64+lane]);
        hv4 y0 = e4[c0+64+lane], y1 = e4[c1+64+lane];
        hv4 y2 = e4[c2+64+lane], y3 = e4[c3+64+lane];
        acc1 += (x0+y0); acc1 += (x1+y1); acc1 += (x2+y2); acc1 += (x3+y3);
      }
    }
    while (i < en){
      int p0 = pk[i]; ++i;
      long b0 = (long)(p0>>5)*80; int c0 = (p0&31)*80;
      acc0 += (bn0(h4[b0+lane]) + e4[c0+lane]);
      if (tl) acc1 += (bn1(h4[b0+64+lane]) + e4[c0+64+lane]);
    }
  }
  hv4* a4 = (hv4*)agg;
  __builtin_nontemporal_store(acc0, &a4[base + lane]);
  if (tl) __builtin_nontemporal_store(acc1, &a4[base + 64 + lane]);
}

// ---------------- FUSED GIN MLP v5: 3 blocks/CU occupancy play ------------------
// Same proven SERIAL schedule (plain __syncthreads) and v4c's harness-verified
// 16x16x32 u-phase math; n1-step 32 (20 iters) so LDS fits 3 blocks/CU:
//   uS  [128][32] XOR-swizzled  = 8 KB   (off ^= (row&7)<<3; bijective, 16B-ok)
//   W1s [32][328]               = 20.5 KB (164 dw === 4 mod 32: 2-way, free)
//   W2s [384][32]               = 24 KB   (r0's exact z-phase B layout)
//   total 52.5 KB -> 3 blocks/CU (was 64 KB -> 2). More co-resident blocks to
//   absorb barrier drains (m114 overlap model); schedule/math unchanged.
// 3 barriers/iter: [stage W1+W2] sync [u-MFMA -> uS] sync [z-MFMA] sync.
__global__ __launch_bounds__(512, 2) void gin_mlp(
    const u16* __restrict__ A,        // [MPAD][320]
    const u16* __restrict__ W1Tl,     // [640][320]
    const u16* __restrict__ b1l,      // [600]
    const u16* __restrict__ W2Tl,     // [384][640]
    const u16* __restrict__ b2l,      // [300]
    u16* __restrict__ Z,              // [MPAD][320]
    float* __restrict__ colsum, float* __restrict__ colsumsq)
{
  __shared__ __align__(16) u16 lds[26880];   // 53760 B = 52.5 KB
  u16* uS  = lds;                  // 4096 u16, swizzled
  u16* W1s = lds + 4096;           // 10496 u16
  u16* W2s = lds + 4096 + 10496;   // 12288 u16
  int tid = threadIdx.x;
  int wave = tid>>6, lane = tid&63;
  int q = lane>>4, r = lane&15;
  int rg = wave>>1, ch = wave&1;    // u-phase: rows rg*32, col-16-half ch
  int wr = wave>>2, wc = wave&3;    // z-phase: rows wr*64, cols wc*96
  int m0 = blockIdx.x*128;

  // A rows into regs, 16x16x32 A-layout (v4c-verified): m = r, k = q*8 + e
  half8 aReg0[10], aReg1[10];
  {
    const u16* Arow0 = A + (long)(m0 + rg*32 + r)*320 + q*8;
    const u16* Arow1 = A + (long)(m0 + rg*32 + 16 + r)*320 + q*8;
    #pragma unroll
    for (int kc=0; kc<10; ++kc){
      aReg0[kc] = *(const half8*)(Arow0 + kc*32);
      aReg1[kc] = *(const half8*)(Arow1 + kc*32);
    }
  }

  float4v zacc[4][6];
  #pragma unroll
  for (int i=0;i<4;i++)
    #pragma unroll
    for (int j=0;j<6;j++) zacc[i][j] = (float4v){0.f,0.f,0.f,0.f};

  for (int t1=0; t1<20; ++t1){
    int n1_0 = t1*32;
    __syncthreads();   // prior u done with W1s; prior z done with uS/W2s
    // stage W1 tile [32 n1][328 k] = 1312 16B-chunks (41 chunks/row, k8<40 real)
    #pragma unroll
    for (int rnd=0; rnd<3; ++rnd){
      int c = rnd*512 + tid;
      if (c < 1312){
        int n = c/41, k8 = c - n*41;
        const u16* src = (k8 < 40) ? (W1Tl + (long)(n1_0 + n)*320 + k8*8) : W1Tl;
        g2l16(src, W1s + c*8);
      }
    }
    // stage W2 tile [384 n][32 k] = 1536 chunks, exactly 3/thread
    #pragma unroll
    for (int rnd=0; rnd<3; ++rnd){
      int i = rnd*512 + tid;
      int n2 = i>>2, k8 = (i&3)*8;
      g2l16(W2Tl + (long)n2*640 + n1_0 + k8, W2s + i*8);
    }
    __syncthreads();   // staged tiles visible (compiler drains vmcnt at barrier)

    // ---- u-phase: u[rg*32..+32][ch*16..+16] via 16x16x32, shared B read ----
    float4v ua0 = (float4v){0.f,0.f,0.f,0.f}, ua1 = (float4v){0.f,0.f,0.f,0.f};
    #pragma unroll
    for (int kc=0; kc<10; ++kc){
      half8 bw = *(const half8*)&W1s[(ch*16 + r)*328 + kc*32 + q*8];
      ua0 = __builtin_amdgcn_mfma_f32_16x16x32_f16(aReg0[kc], bw, ua0, 0,0,0);
      ua1 = __builtin_amdgcn_mfma_f32_16x16x32_f16(aReg1[kc], bw, ua1, 0,0,0);
    }
    // bias + relu + swizzled uS write (C-layout: row = q*4+reg, col = r)
    {
      int col = ch*16 + r;
      int n1c = n1_0 + col;
      float bv = (n1c < 600) ? h2f(b1l[n1c]) : 0.f;
      #pragma unroll
      for (int reg=0; reg<4; ++reg){
        int row0 = rg*32 + q*4 + reg;
        int row1 = row0 + 16;            // (row1&7)==(row0&7): same XOR
        uS[(row0*32 + col) ^ ((row0&7)<<3)] = f2h(fmaxf(ua0[reg] + bv, 0.f));
        uS[(row1*32 + col) ^ ((row1&7)<<3)] = f2h(fmaxf(ua1[reg] + bv, 0.f));
      }
    }
    __syncthreads();   // u visible

    // ---- z-phase: 4x6 tiles (r0 decomposition), K = 32 ----
    half8 af[4], bf[6];
    #pragma unroll
    for (int i=0;i<4;i++){
      int row = wr*64 + i*16 + r;
      af[i] = *(const half8*)&uS[(row*32 + q*8) ^ ((row&7)<<3)];
    }
    #pragma unroll
    for (int j=0;j<6;j++) bf[j] = *(const half8*)&W2s[(wc*96 + j*16 + r)*32 + q*8];
    #pragma unroll
    for (int i=0;i<4;i++)
      #pragma unroll
      for (int j=0;j<6;j++)
        zacc[i][j] = __builtin_amdgcn_mfma_f32_16x16x32_f16(af[i], bf[j], zacc[i][j], 0,0,0);
  }

  // epilogue (r0-identical): bias + fp16 store (cols<320, cached) + BN stats
  #pragma unroll
  for (int j=0;j<6;j++){
    int c = wc*96 + j*16 + r;
    float bv = (c < 300) ? h2f(b2l[c]) : 0.f;
    float s1 = 0.f, s2 = 0.f;
    #pragma unroll
    for (int i=0;i<4;i++){
      int rowb = m0 + wr*64 + i*16 + q*4;
      #pragma unroll
      for (int t=0;t<4;t++){
        float v = zacc[i][j][t] + bv;
        int gr = rowb + t;
        if (c < 320) Z[(long)gr*320 + c] = f2h(v);
        if (gr < NN){ s1 += v; s2 += v*v; }
      }
    }
    s1 += __shfl_xor(s1,16); s1 += __shfl_xor(s1,32);
    s2 += __shfl_xor(s2,16); s2 += __shfl_xor(s2,32);
    if (q == 0 && c < 384){ atomicAdd(&colsum[c], s1); atomicAdd(&colsumsq[c], s2); }
  }
}

// ---------------- MFMA GEMM (fp16), ring-3 counted-vmcnt pipeline ---------------
// Tail projectors + logits only (r3/r4-proven). omode: 2=fp16, 1=bf16, 0=fp32.
__global__ __launch_bounds__(256) void gemm_nt(
    const u16* __restrict__ A, int lda,
    const u16* __restrict__ BT, int ldb,
    int Kp,
    const u16* __restrict__ bias, int Nreal,
    float scale, int dorelu, int omode, int Ncap,
    void* __restrict__ Cv, int ldc,
    const int* __restrict__ outmode)
{
  __shared__ __align__(16) u16 As[3][128*32];
  __shared__ __align__(16) u16 Bs[3][128*32];
  int tid = threadIdx.x;
  int wave = tid>>6, lane = tid&63;
  int wr = (wave>>1)&1, wc = wave&1;
  int nwg  = gridDim.x*gridDim.y;
  int flat = blockIdx.y*gridDim.x + blockIdx.x;
  int qd = nwg>>3, rm = nwg&7;
  int xcd = flat&7, sub = flat>>3;
  int wgid = (xcd<rm ? xcd*(qd+1) : rm*(qd+1)+(xcd-rm)*qd) + sub;
  int nt = wgid % gridDim.x, mt = wgid / gridDim.x;
  int m0 = mt*128, n0 = nt*128;
  int q = lane>>4, r = lane&15;
  int srow = tid>>2, scol = (tid&3)*8;
  const u16* Ag0 = A  + (long)(m0+srow)*lda + scol;
  const u16* Ag1 = A  + (long)(m0+64+srow)*lda + scol;
  const u16* Bg0 = BT + (long)(n0+srow)*ldb + scol;
  const u16* Bg1 = BT + (long)(n0+64+srow)*ldb + scol;
  float4v acc[4][4];
  #pragma unroll
  for (int i=0;i<4;i++)
    #pragma unroll
    for (int j=0;j<4;j++) acc[i][j] = (float4v){0.f,0.f,0.f,0.f};

  int nk = Kp >> 5;
  {
    g2l16(Ag0, &As[0][tid*8]);     g2l16(Ag1, &As[0][2048+tid*8]);
    g2l16(Bg0, &Bs[0][tid*8]);     g2l16(Bg1, &Bs[0][2048+tid*8]);
    if (nk > 1){
      g2l16(Ag0+32, &As[1][tid*8]);  g2l16(Ag1+32, &As[1][2048+tid*8]);
      g2l16(Bg0+32, &Bs[1][tid*8]);  g2l16(Bg1+32, &Bs[1][2048+tid*8]);
    }
  }
  for (int t=0; t<nk; ++t){
    int cur = t % 3;
    if (t+1 < nk) asm volatile("s_waitcnt vmcnt(4)" ::: "memory");
    else          asm volatile("s_waitcnt vmcnt(0)" ::: "memory");
    __builtin_amdgcn_s_barrier();
    if (t+2 < nk){
      int b = (t+2)%3, k0 = (t+2)*32;
      g2l16(Ag0+k0, &As[b][tid*8]);  g2l16(Ag1+k0, &As[b][2048+tid*8]);
      g2l16(Bg0+k0, &Bs[b][tid*8]);  g2l16(Bg1+k0, &Bs[b][2048+tid*8]);
    }
    half8 af[4], bf[4];
    #pragma unroll
    for (int i=0;i<4;i++) af[i] = *(const half8*)&As[cur][(wr*64+i*16+r)*32 + q*8];
    #pragma unroll
    for (int j=0;j<4;j++) bf[j] = *(const half8*)&Bs[cur][(wc*64+j*16+r)*32 + q*8];
    #pragma unroll
    for (int i=0;i<4;i++)
      #pragma unroll
      for (int j=0;j<4;j++)
        acc[i][j] = __builtin_amdgcn_mfma_f32_16x16x32_f16(af[i], bf[j], acc[i][j], 0,0,0);
  }

  int ob = omode;
  if (outmode) ob = (*outmode) ? 0 : 1;   // fp32 inputs -> fp32 logits, else bf16
  u16* Ch = (u16*)Cv; float* Cf = (float*)Cv;
  #pragma unroll
  for (int j=0;j<4;j++){
    int c = n0 + wc*64 + j*16 + r;
    float bv = (bias && c < Nreal) ? h2f(bias[c]) : 0.f;
    #pragma unroll
    for (int i=0;i<4;i++){
      int rowb = m0 + wr*64 + i*16 + q*4;
      #pragma unroll
      for (int tt=0; tt<4; ++tt){
        float v = acc[i][j][tt] + bv;
        if (dorelu) v = fmaxf(v, 0.f);
        v *= scale;
        int gr = rowb + tt;
        if (c < Ncap){
          long o = (long)gr*ldc + c;
          if (ob == 2)      Ch[o] = f2h(v);
          else if (ob == 1) Ch[o] = f2b(v);
          else              Cf[o] = v;
        }
      }
    }
  }
}

// ---------------- batchnorm ----------------
// c in [300,320): sc=sh=0 so the fused-BN path forces pad cols to exactly 0
__global__ __launch_bounds__(320) void bn_finalize(const float* __restrict__ st, const u16* __restrict__ g,
                                                   const u16* __restrict__ b, float* __restrict__ sc,
                                                   float* __restrict__ sh){
  int c = threadIdx.x;
  if (c >= 300){ sc[c] = 0.f; sh[c] = 0.f; return; }
  float mu  = st[c] * (1.0f/NN);
  float var = st[384+c] * (1.0f/NN) - mu*mu;
  float inv = rsqrtf(var + 1e-5f);
  float gg = h2f(g[c]) * inv;
  sc[c] = gg; sh[c] = h2f(b[c]) - mu*gg;
}
// vectorized: 8 halves (16 B) per thread (r4-proven). Used ONCE per branch
// (final layer, no relu) — intermediate layers fuse BN into aggregate.
__global__ __launch_bounds__(256) void bn_apply(const u16* __restrict__ z, const float* __restrict__ sc,
                                                const float* __restrict__ sh, u16* __restrict__ h, int dorelu){
  int idx = blockIdx.x*256 + threadIdx.x;
  if (idx >= NN*40) return;
  int n = idx/40, p = idx - n*40;
  short8v zz = ((const short8v*)z)[(long)n*40 + p];
  short8v out;
  #pragma unroll
  for (int e=0; e<8; ++e){
    int d = p*8 + e;
    float v = h2f((u16)zz[e])*sc[d] + sh[d];
    if (dorelu) v = fmaxf(v, 0.f);
    out[e] = (short)f2h(v);
    if (d >= 300) out[e] = 0;
  }
  ((short8v*)h)[(long)n*40 + p] = out;
}

// ---------------- pooling / branch tail ----------------
__global__ __launch_bounds__(256) void graph_starts(const int* __restrict__ ids, int* __restrict__ starts){
  int i = blockIdx.x*256 + threadIdx.x;
  if (i >= NN) return;
  int b = ids[i];
  if (i == 0){ for (int g=0; g<=b; ++g) starts[g] = 0; }
  else { int p = ids[i-1]; for (int g=p+1; g<=b; ++g) starts[g] = i; }
  if (i == NN-1){ for (int g=b+1; g<=NG; ++g) starts[g] = NN; }
}
__global__ __launch_bounds__(256) void pool_kernel(const u16* __restrict__ h, const int* __restrict__ starts,
                                                   u16* __restrict__ pooled){
  int g = blockIdx.x*4 + (threadIdx.x>>6);
  int lane = threadIdx.x & 63;
  if (g >= NG) return;
  int s = starts[g], e = starts[g+1];
  int cnt = e - s; if (cnt < 1) cnt = 1;
  float inv = 1.0f/(float)cnt;
  float ax[3] = {0,0,0}, ay[3] = {0,0,0};
  const ushort2* h2 = (const ushort2*)h;
  for (int row=s; row<e; ++row){
    long base = (long)row*160;
    #pragma unroll
    for (int jp=0; jp<3; ++jp){
      int p = jp*64 + lane;
      if (p < 160){ ushort2 v = h2[base+p]; ax[jp] += h2f(v.x); ay[jp] += h2f(v.y); }
    }
  }
  ushort2* o2 = (ushort2*)pooled;
  #pragma unroll
  for (int jp=0; jp<3; ++jp){
    int p = jp*64 + lane;
    if (p < 160) o2[g*160+p] = make_ushort2(f2h(ax[jp]*inv), f2h(ay[jp]*inv));
  }
}
__global__ __launch_bounds__(256) void gather_rows(const u16* __restrict__ h, const int* __restrict__ idxs,
                                                   u16* __restrict__ out){
  int idx = blockIdx.x*256 + threadIdx.x;
  if (idx >= NG*160) return;
  int g = idx/160, p = idx - g*160;
  ((ushort2*)out)[idx] = ((const ushort2*)h)[(long)idxs[g]*160 + p];
}
__global__ __launch_bounds__(256) void add_norm(const float* __restrict__ vp, const float* __restrict__ vd,
                                                u16* __restrict__ f){
  int g = blockIdx.x*4 + (threadIdx.x>>6);
  int lane = threadIdx.x & 63;
  if (g >= NG) return;
  float vals[5]; float ss = 0.f;
  #pragma unroll
  for (int t=0; t<5; ++t){
    int d = lane + 64*t; float v = 0.f;
    if (d < 300) v = vp[g*320+d] + vd[g*320+d];
    vals[t] = v; ss += v*v;
  }
  #pragma unroll
  for (int off=32; off>0; off>>=1) ss += __shfl_xor(ss, off);
  float inv = rsqrtf(ss);
  #pragma unroll
  for (int t=0; t<5; ++t){
    int d = lane + 64*t;
    if (d < 320) f[g*320+d] = f2h(d < 300 ? vals[t]*inv : 0.f);
  }
}

// ---------------- host orchestration ----------------
extern "C" void kernel_launch(void* const* d_in, const int* in_sizes, int n_in,
                              void* d_out, int out_size, void* d_ws, size_t ws_size,
                              hipStream_t stream)
{
  const int* xin[2]  = {(const int*)d_in[0], (const int*)d_in[5]};
  const int* ei[2]   = {(const int*)d_in[1], (const int*)d_in[6]};
  const int* ea[2]   = {(const int*)d_in[2], (const int*)d_in[7]};
  const int* bid[2]  = {(const int*)d_in[3], (const int*)d_in[8]};
  const int* dang[2] = {(const int*)d_in[4], (const int*)d_in[9]};
  (void)in_sizes; (void)n_in; (void)out_size; (void)ws_size;

  char* w = (char*)d_ws;
  auto alloc = [&](size_t bytes)->char* {
    char* p = w; w += (bytes + 255) & ~(size_t)255; return p;
  };
  // big buffers, FIXED roles:
  //   Zb: node_init out / gin_mlp z out — random-gather source, written CACHED.
  //   Gb: aggregate out / gin_mlp A in — stream-once, NT.
  u16* Zb   = (u16*)alloc((size_t)MPAD*320*2);   // 64.06 MB
  u16* Gb   = (u16*)alloc((size_t)MPAD*320*2);   // 64.06 MB
  // tail buffers
  u16*   pooled = (u16*)alloc((size_t)NG*320*2);
  u16*   hd     = (u16*)alloc((size_t)NG*320*2);
  u16*   ubuf   = (u16*)alloc((size_t)NG*384*2);
  float* vpb    = (float*)alloc((size_t)NG*320*4);
  float* vdb    = (float*)alloc((size_t)NG*320*4);
  // small buffers
  u16* ec   = (u16*)alloc((size_t)LL*18*320*2);
  u16* W1T  = (u16*)alloc((size_t)LL*640*320*2);
  u16* W2T  = (u16*)alloc((size_t)LL*384*640*2);
  u16* pW1T = (u16*)alloc((size_t)4*384*320*2);
  u16* pW2T = (u16*)alloc((size_t)4*384*384*2);
  int* counts = (int*)alloc((size_t)NN*4);
  int* cursor = (int*)alloc((size_t)NN*4);
  int* offs   = (int*)alloc((size_t)(NN+1)*4);
  int* perm   = (int*)alloc((size_t)NE*4);
  int* csums  = (int*)alloc(512);
  int* cbase  = (int*)alloc(512);
  float* stats = (float*)alloc(768*4);
  float* bnsc  = (float*)alloc(384*4);
  float* bnsh  = (float*)alloc(384*4);
  int* starts  = (int*)alloc((size_t)(NG+1)*4);
  u16* f0b     = (u16*)alloc((size_t)NG*320*2);
  u16* f1b     = (u16*)alloc((size_t)NG*320*2);
  int* dflag   = (int*)alloc(256);
  // fp16 param arena
  const int pcnt[14] = {36000, 900, 9000, 4500, 900000, 3000, 900000, 1500,
                        1500, 1500, 360000, 1200, 360000, 1200};
  u16* parena = (u16*)alloc((size_t)2580300*2 + 14*256);
  u16* pp[14];
  { size_t off = 0;
    for (int i=0;i<14;i++){ pp[i] = parena + off; off += (size_t)((pcnt[i]+127)&~127); } }
  u16* ae1 = pp[0];  u16* ae2 = pp[1];  u16* ee1 = pp[2];  u16* ee2 = pp[3];
  u16* W1  = pp[4];  u16* b1  = pp[5];  u16* W2  = pp[6];  u16* b2  = pp[7];
  u16* bng = pp[8];  u16* bnb = pp[9];  u16* pW1 = pp[10]; u16* pb1 = pp[11];
  u16* pW2 = pp[12]; u16* pb2 = pp[13];

  auto cdiv = [](long a, long b){ return (int)((a + b - 1)/b); };
  // gx = N-tiles (blockIdx.x, fast), gy = M-tiles (blockIdx.y)
  auto gemm = [&](const u16* A, int lda, const u16* BT, int ldb, int Kp,
                  const u16* bias, int Nreal, float scale, int relu, int omode, int Ncap,
                  void* C, int ldc, int gx, int gy, const int* om){
    gemm_nt<<<dim3(gx,gy), 256, 0, stream>>>(A,lda,BT,ldb,Kp,bias,Nreal,scale,relu,omode,Ncap,
                                             C,ldc,om);
  };

  // ---- dtype probe + param normalization ----
  zero32<<<1,256,0,stream>>>((unsigned*)dflag, 1);
  detect_dtype<<<16,256,0,stream>>>((const u16*)d_in[14], dflag);
  for (int i=0;i<14;i++)
    cvt_param<<<cdiv(pcnt[i],256),256,0,stream>>>(d_in[10+i], pp[i], pcnt[i], dflag);

  // weight prep
  tpad<<<cdiv((long)LL*640*320,256),256,0,stream>>>(W1,  W1T,  LL, 300, 600, 320, 640);
  tpad<<<cdiv((long)LL*384*640,256),256,0,stream>>>(W2,  W2T,  LL, 600, 300, 640, 384);
  tpad<<<cdiv((long)4*384*320,256),256,0,stream>>>(pW1, pW1T, 4,  300, 300, 320, 384);
  tpad<<<cdiv((long)4*384*384,256),256,0,stream>>>(pW2, pW2T, 4,  300, 300, 384, 384);
  ecomb_build<<<cdiv((long)LL*18*160,256),256,0,stream>>>(ee1, ee2, ec);

  for (int br=0; br<2; ++br){
    u16* fo = br ? f1b : f0b;
    node_init<<<cdiv((long)MPAD*160,256),256,0,stream>>>(xin[br], ae1, ae2, Zb);
    // CSR by dst
    zero32<<<cdiv(NN,256),256,0,stream>>>((unsigned*)counts, NN);
    hist<<<cdiv(NE,256),256,0,stream>>>(ei[br], counts);
    scan_chunks<<<NCHUNK,256,0,stream>>>(counts, csums);
    scan_base<<<1,128,0,stream>>>(csums, cbase, offs);
    scan_final<<<NCHUNK,256,0,stream>>>(counts, cbase, offs);
    zero32<<<cdiv(NN,256),256,0,stream>>>((unsigned*)cursor, NN);
    fill_perm<<<cdiv(NE,256),256,0,stream>>>(ei[br], ea[br], offs, cursor, perm);

    for (int l=0; l<LL; ++l){
      // aggregate applies relu(BN(l-1)) to the gathered source on the fly
      aggregate<<<MPAD/4,256,0,stream>>>(Zb, ec + (size_t)l*18*320, offs, perm, Gb,
                                         bnsc, bnsh, (l > 0) ? 1 : 0);
      zero32<<<3,256,0,stream>>>((unsigned*)stats, 768);
      gin_mlp<<<MPAD/128, 512, 0, stream>>>(Gb,
          W1T + (size_t)l*640*320, b1 + l*600,
          W2T + (size_t)l*384*640, b2 + l*300,
          Zb, stats, stats+384);
      bn_finalize<<<1,320,0,stream>>>(stats, bng + l*300, bnb + l*300, bnsc, bnsh);
    }
    // final BN (layer 4, no relu) materialized once for pool/gather
    bn_apply<<<cdiv((long)NN*40,256),256,0,stream>>>(Zb, bnsc, bnsh, Gb, 0);

    graph_starts<<<cdiv(NN,256),256,0,stream>>>(bid[br], starts);
    pool_kernel<<<NG/4,256,0,stream>>>(Gb, starts, pooled);
    gather_rows<<<cdiv((long)NG*160,256),256,0,stream>>>(Gb, dang[br], hd);

    int pi = br, dpi = 2 + br;
    gemm(pooled, 320, pW1T + (size_t)pi*384*320, 320, 320,
         pb1 + pi*300, 300, 1.f, 1, 2, 384, ubuf, 384, 3, NG/128, nullptr);
    gemm(ubuf, 384, pW2T + (size_t)pi*384*384, 384, 384,
         pb2 + pi*300, 300, 1.f, 0, 0, 320, vpb, 320, 3, NG/128, nullptr);
    gemm(hd, 320, pW1T + (size_t)dpi*384*320, 320, 320,
         pb1 + dpi*300, 300, 1.f, 1, 2, 384, ubuf, 384, 3, NG/128, nullptr);
    gemm(ubuf, 384, pW2T + (size_t)dpi*384*384, 384, 384,
         pb2 + dpi*300, 300, 1.f, 0, 0, 320, vdb, 320, 3, NG/128, nullptr);
    add_norm<<<NG/4,256,0,stream>>>(vpb, vdb, fo);
  }

  // logits = (f0 @ f1^T) / 0.04 -> dtype per detected mode (fp32 here)
  gemm(f0b, 320, f1b, 320, 320, nullptr, 0, 25.0f, 0, 1, NG,
       d_out, NG, NG/128, NG/128, dflag);
}

// Round 12
// 3541.990 us; speedup vs baseline: 1.0664x; 1.0664x over previous
//
#include <hip/hip_runtime.h>

// ---------------- constants ----------------
#define NN    100000      // nodes per batch
#define NE    400000      // edges per batch
#define NG    4096        // graphs
#define LL    5
#define MPAD  100096      // 782*128
#define NCHUNK 98         // ceil(NN/1024)

typedef unsigned short u16;
typedef __attribute__((ext_vector_type(8))) _Float16 half8;
typedef __attribute__((ext_vector_type(4))) _Float16 hv4;
typedef __attribute__((ext_vector_type(4))) float float4v;
typedef __attribute__((ext_vector_type(16))) float float16v;
typedef __attribute__((ext_vector_type(8))) short short8v;

// bf16 decode/encode (for dtype probe + bf16-output fallback)
__device__ __forceinline__ float b2f(u16 u){
  union { float f; unsigned u; } c; c.u = ((unsigned)u)<<16; return c.f;
}
__device__ __forceinline__ u16 f2b(float f){
  union { float f; unsigned u; } c; c.f = f;
  unsigned x = c.u;
  return (u16)((x + 0x7fffu + ((x>>16)&1u)) >> 16);
}
// fp16 decode/encode (pipeline precision)
__device__ __forceinline__ float h2f(u16 u){
  union { u16 s; _Float16 h; } c; c.s = u; return (float)c.h;
}
__device__ __forceinline__ u16 f2h(float f){
  union { u16 s; _Float16 h; } c; c.h = (_Float16)f; return c.s;
}
__device__ __forceinline__ void g2l16(const u16* g, u16* l){
  __builtin_amdgcn_global_load_lds((const __attribute__((address_space(1))) void*)g,
                                   (__attribute__((address_space(3))) void*)l, 16, 0, 0);
}

// ---------------- dtype detection / normalization ----------------
__global__ __launch_bounds__(256) void detect_dtype(const u16* __restrict__ p, int* __restrict__ flag){
  int i = blockIdx.x*256 + threadIdx.x;   // 16 blocks -> 4096 halves
  float v = b2f(p[i]);
  if (!(fabsf(v) <= 1e4f)) atomicOr(flag, 1);
}
__global__ __launch_bounds__(256) void cvt_param(const void* __restrict__ src, u16* __restrict__ dst,
                                                 int n, const int* __restrict__ flag){
  int i = blockIdx.x*256 + threadIdx.x;
  if (i >= n) return;
  float v = (*flag) ? ((const float*)src)[i] : b2f(((const u16*)src)[i]);
  dst[i] = f2h(v);
}

// ---------------- small utility kernels ----------------
__global__ __launch_bounds__(256) void zero32(unsigned* __restrict__ p, int n){
  int i = blockIdx.x*256 + threadIdx.x;
  if (i < n) p[i] = 0u;
}

// transpose+pad: dst[l][n][k] = src[l][k][n], zero outside (fp16 elements)
__global__ __launch_bounds__(256) void tpad(const u16* __restrict__ src, u16* __restrict__ dst,
                                            int L, int K, int N, int Kp, int Np){
  int idx = blockIdx.x*256 + threadIdx.x;
  if (idx >= L*Np*Kp) return;
  int l = idx/(Np*Kp); int r = idx - l*Np*Kp; int n = r/Kp; int k = r - n*Kp;
  dst[idx] = (n<N && k<K) ? src[(l*K + k)*N + n] : (u16)0;
}

// ecomb[l][c][0:320] = eemb1[l][c/3] + eemb2[l][c%3], cols>=300 zero. fp16.
__global__ __launch_bounds__(256) void ecomb_build(const u16* __restrict__ ee1, const u16* __restrict__ ee2,
                                                   u16* __restrict__ ec){
  int idx = blockIdx.x*256 + threadIdx.x;
  if (idx >= LL*18*160) return;
  int l = idx/(18*160); int r = idx - l*18*160; int c = r/160; int p = r - c*160;
  int a0 = c/3, a1 = c - a0*3;
  u16 o0=0,o1=0;
  if (p < 150){
    int d = 2*p;
    o0 = f2h(h2f(ee1[(l*6+a0)*300+d  ]) + h2f(ee2[(l*3+a1)*300+d  ]));
    o1 = f2h(h2f(ee1[(l*6+a0)*300+d+1]) + h2f(ee2[(l*3+a1)*300+d+1]));
  }
  ((ushort2*)ec)[idx] = make_ushort2(o0,o1);
}

// h[n][0:320] = atom_emb1[x[n,0]] + atom_emb2[x[n,1]]; pads zero (fp16)
__global__ __launch_bounds__(256) void node_init(const int* __restrict__ x, const u16* __restrict__ ae1,
                                                 const u16* __restrict__ ae2, u16* __restrict__ h){
  int idx = blockIdx.x*256 + threadIdx.x;
  if (idx >= MPAD*160) return;
  int n = idx/160, p = idx - n*160;
  u16 o0=0,o1=0;
  if (n < NN && p < 150){
    int a = x[2*n], ch = x[2*n+1];
    int d = 2*p;
    o0 = f2h(h2f(ae1[a*300+d  ]) + h2f(ae2[ch*300+d  ]));
    o1 = f2h(h2f(ae1[a*300+d+1]) + h2f(ae2[ch*300+d+1]));
  }
  ((ushort2*)h)[idx] = make_ushort2(o0,o1);
}

// ---------------- CSR build ----------------
__global__ __launch_bounds__(256) void hist(const int* __restrict__ ei, int* __restrict__ counts){
  int e = blockIdx.x*256 + threadIdx.x;
  if (e >= NE) return;
  atomicAdd(&counts[ei[NE + e]], 1);
}
__global__ __launch_bounds__(256) void scan_chunks(const int* __restrict__ counts, int* __restrict__ csums){
  __shared__ int sd[256];
  int base = blockIdx.x*1024;
  int s = 0;
  for (int i = threadIdx.x; i < 1024; i += 256){ int g = base+i; if (g < NN) s += counts[g]; }
  sd[threadIdx.x] = s; __syncthreads();
  for (int off=128; off>0; off>>=1){ if (threadIdx.x < off) sd[threadIdx.x] += sd[threadIdx.x+off]; __syncthreads(); }
  if (threadIdx.x == 0) csums[blockIdx.x] = sd[0];
}
__global__ __launch_bounds__(128) void scan_base(const int* __restrict__ csums, int* __restrict__ cbase,
                                                 int* __restrict__ offsets){
  __shared__ int sd[128];
  int tid = threadIdx.x;
  int v = (tid < NCHUNK) ? csums[tid] : 0;
  sd[tid] = v; __syncthreads();
  for (int off=1; off<128; off<<=1){
    int t = (tid >= off) ? sd[tid-off] : 0; __syncthreads();
    sd[tid] += t; __syncthreads();
  }
  if (tid < NCHUNK) cbase[tid] = sd[tid] - v;
  if (tid == 0) offsets[NN] = sd[NCHUNK-1];
}
__global__ __launch_bounds__(256) void scan_final(const int* __restrict__ counts, const int* __restrict__ cbase,
                                                  int* __restrict__ offsets){
  __shared__ int sd[256];
  int tid = threadIdx.x;
  int base = blockIdx.x*1024 + tid*4;
  int v0 = (base   < NN) ? counts[base  ] : 0;
  int v1 = (base+1 < NN) ? counts[base+1] : 0;
  int v2 = (base+2 < NN) ? counts[base+2] : 0;
  int v3 = (base+3 < NN) ? counts[base+3] : 0;
  int s = v0+v1+v2+v3;
  sd[tid] = s; __syncthreads();
  for (int off=1; off<256; off<<=1){
    int t = (tid >= off) ? sd[tid-off] : 0; __syncthreads();
    sd[tid] += t; __syncthreads();
  }
  int run = cbase[blockIdx.x] + sd[tid] - s;
  if (base   < NN){ offsets[base  ] = run; } run += v0;
  if (base+1 < NN){ offsets[base+1] = run; } run += v1;
  if (base+2 < NN){ offsets[base+2] = run; } run += v2;
  if (base+3 < NN){ offsets[base+3] = run; }
}
// pack src*32+combo so aggregate needs ONE load per edge
__global__ __launch_bounds__(256) void fill_perm(const int* __restrict__ ei, const int* __restrict__ ea,
                                                 const int* __restrict__ offsets,
                                                 int* __restrict__ cursor, int* __restrict__ pk){
  int e = blockIdx.x*256 + threadIdx.x;
  if (e >= NE) return;
  int d = ei[NE + e];
  int src = ei[e];
  int c = ea[2*e]*3 + ea[2*e+1];
  int pos = offsets[d] + atomicAdd(&cursor[d], 1);
  pk[pos] = src*32 + c;
}

// ---------------- aggregation (wave/node, packed fp16 adds, 4-edge unroll) ------
// agg writes are NON-TEMPORAL: agg is write-once here / streamed-once by gin_mlp,
// so keep it out of L2/L3 to preserve L3 residency of h for the random gather.
__global__ __launch_bounds__(256) void aggregate(
    const u16* __restrict__ h, const u16* __restrict__ ecL,
    const int* __restrict__ offsets, const int* __restrict__ pk,
    u16* __restrict__ agg)
{
  __shared__ u16 ecs[18*320];
  for (int i = threadIdx.x; i < 18*160; i += 256)
    ((ushort2*)ecs)[i] = ((const ushort2*)ecL)[i];
  __syncthreads();
  int node = blockIdx.x*4 + (threadIdx.x>>6);
  int lane = threadIdx.x & 63;
  bool tl = lane < 16;
  const hv4* h4 = (const hv4*)h;
  const hv4* e4 = (const hv4*)ecs;
  long base = (long)node*80;
  hv4 acc0, acc1 = (hv4)(_Float16)0;
  // self: h + ec[12] (bond 4, dir 0)
  acc0 = h4[base + lane] + e4[12*80 + lane];
  if (tl) acc1 = h4[base + 64 + lane] + e4[12*80 + 64 + lane];
  if (node < NN){
    int s = offsets[node], en = offsets[node+1];
    int i = s;
    while (i + 3 < en){
      int p0 = pk[i], p1 = pk[i+1], p2 = pk[i+2], p3 = pk[i+3]; i += 4;
      long b0 = (long)(p0>>5)*80, b1 = (long)(p1>>5)*80;
      long b2 = (long)(p2>>5)*80, b3 = (long)(p3>>5)*80;
      int c0 = (p0&31)*80, c1 = (p1&31)*80, c2 = (p2&31)*80, c3 = (p3&31)*80;
      hv4 a0 = h4[b0+lane], a1 = h4[b1+lane], a2 = h4[b2+lane], a3 = h4[b3+lane];
      hv4 e0 = e4[c0+lane], e1 = e4[c1+lane], e2 = e4[c2+lane], e3 = e4[c3+lane];
      acc0 += (a0+e0); acc0 += (a1+e1); acc0 += (a2+e2); acc0 += (a3+e3);
      if (tl){
        hv4 x0 = h4[b0+64+lane], x1 = h4[b1+64+lane];
        hv4 x2 = h4[b2+64+lane], x3 = h4[b3+64+lane];
        hv4 y0 = e4[c0+64+lane], y1 = e4[c1+64+lane];
        hv4 y2 = e4[c2+64+lane], y3 = e4[c3+64+lane];
        acc1 += (x0+y0); acc1 += (x1+y1); acc1 += (x2+y2); acc1 += (x3+y3);
      }
    }
    while (i < en){
      int p0 = pk[i]; ++i;
      long b0 = (long)(p0>>5)*80; int c0 = (p0&31)*80;
      acc0 += (h4[b0+lane] + e4[c0+lane]);
      if (tl) acc1 += (h4[b0+64+lane] + e4[c0+64+lane]);
    }
  }
  hv4* a4 = (hv4*)agg;
  __builtin_nontemporal_store(acc0, &a4[base + lane]);
  if (tl) __builtin_nontemporal_store(acc1, &a4[base + 64 + lane]);
}

// ---------------- FUSED GIN MLP (r0-proven): z = relu(A*W1+b1)*W2+b2 + BN -------
// 512 thr / 128 rows. u-phase: 32x32x16 MFMA, A in regs (32 rows per lane-group).
// z-phase: 16x16x32 (verified layout). LDS = uS 16KB + W-region 48KB = 64KB exact.
// W1 tile [64][328] (pad 8 -> stride 164 dw === 4 mod 32, conflict-free staged reads).
// Z stores are NON-TEMPORAL (streamed once by bn_apply; keep L3 for h).
// NOTE (r5-r10 ledger): deep-pipeline/dbuf/occupancy variants all measured SLOWER
// (205-266us vs this kernel's 203): VGPR 124+ caps 2 blocks/CU regardless of LDS,
// and the 4-phase u->z chain defeats source-level pipelining. Keep serial.
__global__ __launch_bounds__(512, 2) void gin_mlp(
    const u16* __restrict__ A,        // [MPAD][320]
    const u16* __restrict__ W1Tl,     // [640][320]
    const u16* __restrict__ b1l,      // [600]
    const u16* __restrict__ W2Tl,     // [384][640]
    const u16* __restrict__ b2l,      // [300]
    u16* __restrict__ Z,              // [MPAD][320]
    float* __restrict__ colsum, float* __restrict__ colsumsq)
{
  __shared__ __align__(16) u16 lds[32768];   // 64 KB
  u16* uS = lds;           // [2][128][32] = 8192 u16
  u16* Ws = lds + 8192;    // W1 [64][328]=20992 u16  |  W2 [2][384][32]=24576 u16
  int tid = threadIdx.x;
  int wave = tid>>6, lane = tid&63;
  int n5 = lane & 31, hi = lane >> 5;   // 32x32 ids
  int q = lane>>4, r = lane&15;         // 16x16 ids
  int rg = wave>>1, ch = wave&1;        // u-phase: rows rg*32, col-half ch
  int wr = wave>>2, wc = wave&3;        // z-phase: rows wr*64, cols wc*96
  int m0 = blockIdx.x*128;

  // A rows into registers (32x32 A-layout: m=n5, k=kc*16+hi*8)
  half8 aReg[20];
  const u16* Arow = A + (long)(m0 + rg*32 + n5)*320 + hi*8;
  #pragma unroll
  for (int kc=0; kc<20; ++kc) aReg[kc] = *(const half8*)(Arow + kc*16);

  float4v zacc[4][6];
  #pragma unroll
  for (int i=0;i<4;i++)
    #pragma unroll
    for (int j=0;j<6;j++) zacc[i][j] = (float4v){0.f,0.f,0.f,0.f};

  for (int t1=0; t1<10; ++t1){
    int n1_0 = t1*64;
    __syncthreads();   // prior z-phase done with uS/Ws
    // stage W1 tile [64 n][328 k] (20992 u16 = 2624 16B-chunks, 41 chunks/row)
    #pragma unroll
    for (int rnd=0; rnd<5; ++rnd){
      int ck = rnd*512 + tid;
      int n = ck/41, k8 = ck - n*41;
      const u16* src = (k8 < 40) ? (W1Tl + (long)(n1_0 + n)*320 + k8*8) : W1Tl;
      g2l16(src, Ws + ck*8);
    }
    if (tid < 64){
      int ck = 2560 + tid;
      int n = ck/41, k8 = ck - n*41;
      const u16* src = (k8 < 40) ? (W1Tl + (long)(n1_0 + n)*320 + k8*8) : W1Tl;
      g2l16(src, Ws + ck*8);
    }
    __syncthreads();
    // u-phase: wave computes u[rg*32..+31][ch*32..+31] via 32x32x16
    float16v uacc = (float16v)(0.f);
    #pragma unroll
    for (int kc=0; kc<20; ++kc){
      half8 bw = *(const half8*)&Ws[(ch*32 + n5)*328 + kc*16 + hi*8];
      uacc = __builtin_amdgcn_mfma_f32_32x32x16_f16(aReg[kc], bw, uacc, 0,0,0);
    }
    // bias + relu + write u to uS[ch][row][32] (col = n5)
    {
      int n1g = n1_0 + ch*32 + n5;
      float bv = (n1g < 600) ? h2f(b1l[n1g]) : 0.f;
      u16* uw = uS + ch*4096 + n5;
      #pragma unroll
      for (int reg=0; reg<16; ++reg){
        int row = rg*32 + (reg&3) + 8*(reg>>2) + 4*hi;
        float v = fmaxf(uacc[reg] + bv, 0.f);
        uw[row*32] = f2h(v);
      }
    }
    __syncthreads();   // u visible; W1 reads done
    // stage W2 tile [2 kc2][384 n][32 k]
    #pragma unroll
    for (int i=0;i<6;i++){
      int idx = tid*8 + i*4096;
      int kc2 = idx / 12288;
      int rem = idx - kc2*12288;
      int n2 = rem >> 5, k8 = rem & 31;
      g2l16(W2Tl + (long)n2*640 + n1_0 + kc2*32 + k8, Ws + idx);
    }
    __syncthreads();
    // z-phase: 16x16x32, K = 64 (2 chunks)
    #pragma unroll
    for (int kc2=0; kc2<2; ++kc2){
      half8 af[4], bf[6];
      #pragma unroll
      for (int i=0;i<4;i++) af[i] = *(const half8*)&uS[kc2*4096 + (wr*64+i*16+r)*32 + q*8];
      #pragma unroll
      for (int j=0;j<6;j++) bf[j] = *(const half8*)&Ws[kc2*12288 + (wc*96+j*16+r)*32 + q*8];
      #pragma unroll
      for (int i=0;i<4;i++)
        #pragma unroll
        for (int j=0;j<6;j++)
          zacc[i][j] = __builtin_amdgcn_mfma_f32_16x16x32_f16(af[i], bf[j], zacc[i][j], 0,0,0);
    }
  }
  // epilogue: bias + fp16 NT store (cols<320) + BN stats (rows<NN)
  #pragma unroll
  for (int j=0;j<6;j++){
    int c = wc*96 + j*16 + r;
    float bv = (c < 300) ? h2f(b2l[c]) : 0.f;
    float s1 = 0.f, s2 = 0.f;
    #pragma unroll
    for (int i=0;i<4;i++){
      int rowb = m0 + wr*64 + i*16 + q*4;
      #pragma unroll
      for (int t=0;t<4;t++){
        float v = zacc[i][j][t] + bv;
        int gr = rowb + t;
        if (c < 320) __builtin_nontemporal_store(f2h(v), &Z[(long)gr*320 + c]);
        if (gr < NN){ s1 += v; s2 += v*v; }
      }
    }
    s1 += __shfl_xor(s1,16); s1 += __shfl_xor(s1,32);
    s2 += __shfl_xor(s2,16); s2 += __shfl_xor(s2,32);
    if (q == 0 && c < 384){ atomicAdd(&colsum[c], s1); atomicAdd(&colsumsq[c], s2); }
  }
}

// ---------------- MFMA GEMM (fp16), ring-3 counted-vmcnt pipeline ---------------
// Tail projectors + logits only. T4: one s_barrier per K-step; per-wave vmcnt(4)
// in steady state. Grid: blockIdx.x = N-tile (fast); bijective XCD swizzle (m204).
// omode: 2 = fp16 out, 1 = bf16 out, 0 = fp32 out.
__global__ __launch_bounds__(256) void gemm_nt(
    const u16* __restrict__ A, int lda,
    const u16* __restrict__ BT, int ldb,
    int Kp,
    const u16* __restrict__ bias, int Nreal,
    float scale, int dorelu, int omode, int Ncap,
    void* __restrict__ Cv, int ldc,
    const int* __restrict__ outmode)
{
  __shared__ __align__(16) u16 As[3][128*32];
  __shared__ __align__(16) u16 Bs[3][128*32];
  int tid = threadIdx.x;
  int wave = tid>>6, lane = tid&63;
  int wr = (wave>>1)&1, wc = wave&1;
  int nwg  = gridDim.x*gridDim.y;
  int flat = blockIdx.y*gridDim.x + blockIdx.x;
  int qd = nwg>>3, rm = nwg&7;
  int xcd = flat&7, sub = flat>>3;
  int wgid = (xcd<rm ? xcd*(qd+1) : rm*(qd+1)+(xcd-rm)*qd) + sub;
  int nt = wgid % gridDim.x, mt = wgid / gridDim.x;
  int m0 = mt*128, n0 = nt*128;
  int q = lane>>4, r = lane&15;
  int srow = tid>>2, scol = (tid&3)*8;
  const u16* Ag0 = A  + (long)(m0+srow)*lda + scol;
  const u16* Ag1 = A  + (long)(m0+64+srow)*lda + scol;
  const u16* Bg0 = BT + (long)(n0+srow)*ldb + scol;
  const u16* Bg1 = BT + (long)(n0+64+srow)*ldb + scol;
  float4v acc[4][4];
  #pragma unroll
  for (int i=0;i<4;i++)
    #pragma unroll
    for (int j=0;j<4;j++) acc[i][j] = (float4v){0.f,0.f,0.f,0.f};

  int nk = Kp >> 5;
  {
    g2l16(Ag0, &As[0][tid*8]);     g2l16(Ag1, &As[0][2048+tid*8]);
    g2l16(Bg0, &Bs[0][tid*8]);     g2l16(Bg1, &Bs[0][2048+tid*8]);
    if (nk > 1){
      g2l16(Ag0+32, &As[1][tid*8]);  g2l16(Ag1+32, &As[1][2048+tid*8]);
      g2l16(Bg0+32, &Bs[1][tid*8]);  g2l16(Bg1+32, &Bs[1][2048+tid*8]);
    }
  }
  for (int t=0; t<nk; ++t){
    int cur = t % 3;
    if (t+1 < nk) asm volatile("s_waitcnt vmcnt(4)" ::: "memory");
    else          asm volatile("s_waitcnt vmcnt(0)" ::: "memory");
    __builtin_amdgcn_s_barrier();
    if (t+2 < nk){
      int b = (t+2)%3, k0 = (t+2)*32;
      g2l16(Ag0+k0, &As[b][tid*8]);  g2l16(Ag1+k0, &As[b][2048+tid*8]);
      g2l16(Bg0+k0, &Bs[b][tid*8]);  g2l16(Bg1+k0, &Bs[b][2048+tid*8]);
    }
    half8 af[4], bf[4];
    #pragma unroll
    for (int i=0;i<4;i++) af[i] = *(const half8*)&As[cur][(wr*64+i*16+r)*32 + q*8];
    #pragma unroll
    for (int j=0;j<4;j++) bf[j] = *(const half8*)&Bs[cur][(wc*64+j*16+r)*32 + q*8];
    #pragma unroll
    for (int i=0;i<4;i++)
      #pragma unroll
      for (int j=0;j<4;j++)
        acc[i][j] = __builtin_amdgcn_mfma_f32_16x16x32_f16(af[i], bf[j], acc[i][j], 0,0,0);
  }

  int ob = omode;
  if (outmode) ob = (*outmode) ? 0 : 1;   // fp32 inputs -> fp32 logits, else bf16
  u16* Ch = (u16*)Cv; float* Cf = (float*)Cv;
  #pragma unroll
  for (int j=0;j<4;j++){
    int c = n0 + wc*64 + j*16 + r;
    float bv = (bias && c < Nreal) ? h2f(bias[c]) : 0.f;
    #pragma unroll
    for (int i=0;i<4;i++){
      int rowb = m0 + wr*64 + i*16 + q*4;
      #pragma unroll
      for (int tt=0; tt<4; ++tt){
        float v = acc[i][j][tt] + bv;
        if (dorelu) v = fmaxf(v, 0.f);
        v *= scale;
        int gr = rowb + tt;
        if (c < Ncap){
          long o = (long)gr*ldc + c;
          if (ob == 2)      Ch[o] = f2h(v);
          else if (ob == 1) Ch[o] = f2b(v);
          else              Cf[o] = v;
        }
      }
    }
  }
}

// ---------------- batchnorm ----------------
__global__ __launch_bounds__(320) void bn_finalize(const float* __restrict__ st, const u16* __restrict__ g,
                                                   const u16* __restrict__ b, float* __restrict__ sc,
                                                   float* __restrict__ sh){
  int c = threadIdx.x;
  if (c >= 300) return;
  float mu  = st[c] * (1.0f/NN);
  float var = st[384+c] * (1.0f/NN) - mu*mu;
  float inv = rsqrtf(var + 1e-5f);
  float gg = h2f(g[c]) * inv;
  sc[c] = gg; sh[c] = h2f(b[c]) - mu*gg;
}
// vectorized: 8 halves (16 B) per thread. Row = 40 chunks of 8; pad cols (>=300)
// written as zero (same net state as r0: node_init zeroed them).
__global__ __launch_bounds__(256) void bn_apply(const u16* __restrict__ z, const float* __restrict__ sc,
                                                const float* __restrict__ sh, u16* __restrict__ h, int dorelu){
  int idx = blockIdx.x*256 + threadIdx.x;
  if (idx >= NN*40) return;
  int n = idx/40, p = idx - n*40;
  short8v zz = ((const short8v*)z)[(long)n*40 + p];
  short8v out;
  #pragma unroll
  for (int e=0; e<8; ++e){
    int d = p*8 + e;
    float v = h2f((u16)zz[e])*sc[d] + sh[d];
    if (dorelu) v = fmaxf(v, 0.f);
    out[e] = (short)f2h(v);
    if (d >= 300) out[e] = 0;
  }
  ((short8v*)h)[(long)n*40 + p] = out;
}

// ---------------- pooling / branch tail ----------------
__global__ __launch_bounds__(256) void graph_starts(const int* __restrict__ ids, int* __restrict__ starts){
  int i = blockIdx.x*256 + threadIdx.x;
  if (i >= NN) return;
  int b = ids[i];
  if (i == 0){ for (int g=0; g<=b; ++g) starts[g] = 0; }
  else { int p = ids[i-1]; for (int g=p+1; g<=b; ++g) starts[g] = i; }
  if (i == NN-1){ for (int g=b+1; g<=NG; ++g) starts[g] = NN; }
}
__global__ __launch_bounds__(256) void pool_kernel(const u16* __restrict__ h, const int* __restrict__ starts,
                                                   u16* __restrict__ pooled){
  int g = blockIdx.x*4 + (threadIdx.x>>6);
  int lane = threadIdx.x & 63;
  if (g >= NG) return;
  int s = starts[g], e = starts[g+1];
  int cnt = e - s; if (cnt < 1) cnt = 1;
  float inv = 1.0f/(float)cnt;
  float ax[3] = {0,0,0}, ay[3] = {0,0,0};
  const ushort2* h2 = (const ushort2*)h;
  for (int row=s; row<e; ++row){
    long base = (long)row*160;
    #pragma unroll
    for (int jp=0; jp<3; ++jp){
      int p = jp*64 + lane;
      if (p < 160){ ushort2 v = h2[base+p]; ax[jp] += h2f(v.x); ay[jp] += h2f(v.y); }
    }
  }
  ushort2* o2 = (ushort2*)pooled;
  #pragma unroll
  for (int jp=0; jp<3; ++jp){
    int p = jp*64 + lane;
    if (p < 160) o2[g*160+p] = make_ushort2(f2h(ax[jp]*inv), f2h(ay[jp]*inv));
  }
}
__global__ __launch_bounds__(256) void gather_rows(const u16* __restrict__ h, const int* __restrict__ idxs,
                                                   u16* __restrict__ out){
  int idx = blockIdx.x*256 + threadIdx.x;
  if (idx >= NG*160) return;
  int g = idx/160, p = idx - g*160;
  ((ushort2*)out)[idx] = ((const ushort2*)h)[(long)idxs[g]*160 + p];
}
__global__ __launch_bounds__(256) void add_norm(const float* __restrict__ vp, const float* __restrict__ vd,
                                                u16* __restrict__ f){
  int g = blockIdx.x*4 + (threadIdx.x>>6);
  int lane = threadIdx.x & 63;
  if (g >= NG) return;
  float vals[5]; float ss = 0.f;
  #pragma unroll
  for (int t=0; t<5; ++t){
    int d = lane + 64*t; float v = 0.f;
    if (d < 300) v = vp[g*320+d] + vd[g*320+d];
    vals[t] = v; ss += v*v;
  }
  #pragma unroll
  for (int off=32; off>0; off>>=1) ss += __shfl_xor(ss, off);
  float inv = rsqrtf(ss);
  #pragma unroll
  for (int t=0; t<5; ++t){
    int d = lane + 64*t;
    if (d < 320) f[g*320+d] = f2h(d < 300 ? vals[t]*inv : 0.f);
  }
}

// ---------------- host orchestration ----------------
extern "C" void kernel_launch(void* const* d_in, const int* in_sizes, int n_in,
                              void* d_out, int out_size, void* d_ws, size_t ws_size,
                              hipStream_t stream)
{
  const int* xin[2]  = {(const int*)d_in[0], (const int*)d_in[5]};
  const int* ei[2]   = {(const int*)d_in[1], (const int*)d_in[6]};
  const int* ea[2]   = {(const int*)d_in[2], (const int*)d_in[7]};
  const int* bid[2]  = {(const int*)d_in[3], (const int*)d_in[8]};
  const int* dang[2] = {(const int*)d_in[4], (const int*)d_in[9]};
  (void)in_sizes; (void)n_in; (void)out_size; (void)ws_size;

  char* w = (char*)d_ws;
  auto alloc = [&](size_t bytes)->char* {
    char* p = w; w += (bytes + 255) & ~(size_t)255; return p;
  };
  // big buffers (z aliases agg: block reads its own A rows before writing them)
  u16* hA   = (u16*)alloc((size_t)MPAD*320*2);   // 64.06 MB
  u16* agg  = (u16*)alloc((size_t)MPAD*320*2);   // 64.06 MB (also "z")
  u16* z    = agg;
  // tail buffers
  u16*   pooled = (u16*)alloc((size_t)NG*320*2);
  u16*   hd     = (u16*)alloc((size_t)NG*320*2);
  u16*   ubuf   = (u16*)alloc((size_t)NG*384*2);
  float* vpb    = (float*)alloc((size_t)NG*320*4);
  float* vdb    = (float*)alloc((size_t)NG*320*4);
  // small buffers
  u16* ec   = (u16*)alloc((size_t)LL*18*320*2);
  u16* W1T  = (u16*)alloc((size_t)LL*640*320*2);
  u16* W2T  = (u16*)alloc((size_t)LL*384*640*2);
  u16* pW1T = (u16*)alloc((size_t)4*384*320*2);
  u16* pW2T = (u16*)alloc((size_t)4*384*384*2);
  int* counts = (int*)alloc((size_t)NN*4);
  int* cursor = (int*)alloc((size_t)NN*4);
  int* offs   = (int*)alloc((size_t)(NN+1)*4);
  int* perm   = (int*)alloc((size_t)NE*4);
  int* csums  = (int*)alloc(512);
  int* cbase  = (int*)alloc(512);
  float* stats = (float*)alloc(768*4);
  float* bnsc  = (float*)alloc(384*4);
  float* bnsh  = (float*)alloc(384*4);
  int* starts  = (int*)alloc((size_t)(NG+1)*4);
  u16* f0b     = (u16*)alloc((size_t)NG*320*2);
  u16* f1b     = (u16*)alloc((size_t)NG*320*2);
  int* dflag   = (int*)alloc(256);
  // fp16 param arena
  const int pcnt[14] = {36000, 900, 9000, 4500, 900000, 3000, 900000, 1500,
                        1500, 1500, 360000, 1200, 360000, 1200};
  u16* parena = (u16*)alloc((size_t)2580300*2 + 14*256);
  u16* pp[14];
  { size_t off = 0;
    for (int i=0;i<14;i++){ pp[i] = parena + off; off += (size_t)((pcnt[i]+127)&~127); } }
  u16* ae1 = pp[0];  u16* ae2 = pp[1];  u16* ee1 = pp[2];  u16* ee2 = pp[3];
  u16* W1  = pp[4];  u16* b1  = pp[5];  u16* W2  = pp[6];  u16* b2  = pp[7];
  u16* bng = pp[8];  u16* bnb = pp[9];  u16* pW1 = pp[10]; u16* pb1 = pp[11];
  u16* pW2 = pp[12]; u16* pb2 = pp[13];

  auto cdiv = [](long a, long b){ return (int)((a + b - 1)/b); };
  // gx = N-tiles (blockIdx.x, fast), gy = M-tiles (blockIdx.y)
  auto gemm = [&](const u16* A, int lda, const u16* BT, int ldb, int Kp,
                  const u16* bias, int Nreal, float scale, int relu, int omode, int Ncap,
                  void* C, int ldc, int gx, int gy, const int* om){
    gemm_nt<<<dim3(gx,gy), 256, 0, stream>>>(A,lda,BT,ldb,Kp,bias,Nreal,scale,relu,omode,Ncap,
                                             C,ldc,om);
  };

  // ---- dtype probe + param normalization ----
  zero32<<<1,256,0,stream>>>((unsigned*)dflag, 1);
  detect_dtype<<<16,256,0,stream>>>((const u16*)d_in[14], dflag);
  for (int i=0;i<14;i++)
    cvt_param<<<cdiv(pcnt[i],256),256,0,stream>>>(d_in[10+i], pp[i], pcnt[i], dflag);

  // weight prep
  tpad<<<cdiv((long)LL*640*320,256),256,0,stream>>>(W1,  W1T,  LL, 300, 600, 320, 640);
  tpad<<<cdiv((long)LL*384*640,256),256,0,stream>>>(W2,  W2T,  LL, 600, 300, 640, 384);
  tpad<<<cdiv((long)4*384*320,256),256,0,stream>>>(pW1, pW1T, 4,  300, 300, 320, 384);
  tpad<<<cdiv((long)4*384*384,256),256,0,stream>>>(pW2, pW2T, 4,  300, 300, 384, 384);
  ecomb_build<<<cdiv((long)LL*18*160,256),256,0,stream>>>(ee1, ee2, ec);

  for (int br=0; br<2; ++br){
    u16* fo = br ? f1b : f0b;
    node_init<<<cdiv((long)MPAD*160,256),256,0,stream>>>(xin[br], ae1, ae2, hA);
    // CSR by dst
    zero32<<<cdiv(NN,256),256,0,stream>>>((unsigned*)counts, NN);
    hist<<<cdiv(NE,256),256,0,stream>>>(ei[br], counts);
    scan_chunks<<<NCHUNK,256,0,stream>>>(counts, csums);
    scan_base<<<1,128,0,stream>>>(csums, cbase, offs);
    scan_final<<<NCHUNK,256,0,stream>>>(counts, cbase, offs);
    zero32<<<cdiv(NN,256),256,0,stream>>>((unsigned*)cursor, NN);
    fill_perm<<<cdiv(NE,256),256,0,stream>>>(ei[br], ea[br], offs, cursor, perm);

    for (int l=0; l<LL; ++l){
      aggregate<<<MPAD/4,256,0,stream>>>(hA, ec + (size_t)l*18*320, offs, perm, agg);
      zero32<<<3,256,0,stream>>>((unsigned*)stats, 768);
      gin_mlp<<<MPAD/128, 512, 0, stream>>>(agg,
          W1T + (size_t)l*640*320, b1 + l*600,
          W2T + (size_t)l*384*640, b2 + l*300,
          z, stats, stats+384);
      bn_finalize<<<1,320,0,stream>>>(stats, bng + l*300, bnb + l*300, bnsc, bnsh);
      bn_apply<<<cdiv((long)NN*40,256),256,0,stream>>>(z, bnsc, bnsh, hA, (l < LL-1) ? 1 : 0);
    }

    graph_starts<<<cdiv(NN,256),256,0,stream>>>(bid[br], starts);
    pool_kernel<<<NG/4,256,0,stream>>>(hA, starts, pooled);
    gather_rows<<<cdiv((long)NG*160,256),256,0,stream>>>(hA, dang[br], hd);

    int pi = br, dpi = 2 + br;
    gemm(pooled, 320, pW1T + (size_t)pi*384*320, 320, 320,
         pb1 + pi*300, 300, 1.f, 1, 2, 384, ubuf, 384, 3, NG/128, nullptr);
    gemm(ubuf, 384, pW2T + (size_t)pi*384*384, 384, 384,
         pb2 + pi*300, 300, 1.f, 0, 0, 320, vpb, 320, 3, NG/128, nullptr);
    gemm(hd, 320, pW1T + (size_t)dpi*384*320, 320, 320,
         pb1 + dpi*300, 300, 1.f, 1, 2, 384, ubuf, 384, 3, NG/128, nullptr);
    gemm(ubuf, 384, pW2T + (size_t)dpi*384*384, 384, 384,
         pb2 + dpi*300, 300, 1.f, 0, 0, 320, vdb, 320, 3, NG/128, nullptr);
    add_norm<<<NG/4,256,0,stream>>>(vpb, vdb, fo);
  }

  // logits = (f0 @ f1^T) / 0.04 -> dtype per detected mode (fp32 here)
  gemm(f0b, 320, f1b, 320, 320, nullptr, 0, 25.0f, 0, 1, NG,
       d_out, NG, NG/128, NG/128, dflag);
}